// Round 4
// baseline (240.574 us; speedup 1.0000x reference)
//
#include <hip/hip_runtime.h>

// int8 quantized conv2d 3x3 s1 p1. B=32 Cin=128 H=W=56 Cout=256.
// Implicit GEMM. A(weights) via 3-deep LDS ring (24KB), B(activations) direct
// global->reg double-buffer (L2/XCD-resident). 256-thr blocks, 128co x 128px,
// 3 blocks/CU. Counted-vmcnt(6) + 1 barrier/chunk, issue-order pinned.
// XCD-swizzled grid.

#define B_    32
#define CIN   128
#define H_    56
#define W_    56
#define COUT  256
#define HP    58
#define WP    58
#define HWP   (H_*W_)        // 3136
#define NPIX  (B_*HWP)       // 100352
#define NCHUNK 18            // K=1152 / 64
#define WCHUNK 16384         // wq bytes per chunk = 256co * 64B

typedef int int4v __attribute__((ext_vector_type(4)));

__device__ __forceinline__ void gld_lds16(const void* g, void* l) {
    __builtin_amdgcn_global_load_lds(
        (const __attribute__((address_space(1))) unsigned int*)g,
        (__attribute__((address_space(3))) unsigned int*)l, 16, 0, 0);
}

// ---------------- fused amax over x and w ----------------
__global__ __launch_bounds__(256) void amax_kernel(const float4* __restrict__ x, long n4x,
                                                   const float4* __restrict__ wt, long n4w,
                                                   unsigned* __restrict__ scales) {
    const float4* p; long n4; unsigned* slot; long start, stride;
    if (blockIdx.x < 2048) {
        p = x; n4 = n4x; slot = scales;
        start = (long)blockIdx.x * 256 + threadIdx.x; stride = 2048L * 256;
    } else {
        p = wt; n4 = n4w; slot = scales + 1;
        start = (long)(blockIdx.x - 2048) * 256 + threadIdx.x; stride = 128L * 256;
    }
    float m = 0.f;
    for (long i = start; i < n4; i += stride) {
        float4 v = p[i];
        m = fmaxf(m, fmaxf(fmaxf(fabsf(v.x), fabsf(v.y)), fmaxf(fabsf(v.z), fabsf(v.w))));
    }
    __shared__ float red[256];
    red[threadIdx.x] = m; __syncthreads();
    for (int s = 128; s > 0; s >>= 1) {
        if (threadIdx.x < s) red[threadIdx.x] = fmaxf(red[threadIdx.x], red[threadIdx.x + s]);
        __syncthreads();
    }
    if (threadIdx.x == 0) atomicMax(slot, __float_as_uint(red[0]));  // all >=0
}

// ---------------- quantize x: NCHW f32 -> padded NHWC int8 (+ border zeroing) ----------------
__global__ __launch_bounds__(256) void quant_x_kernel(const float* __restrict__ x,
        const unsigned* __restrict__ scales, signed char* __restrict__ xq) {
    const int bh = blockIdx.x;
    const int b = bh / H_, h = bh % H_;
    const float sx = 127.0f / __uint_as_float(scales[0]);
    __shared__ int ldsq[W_ * 33];
    const int tid = threadIdx.x;

    // ---- border padding; disjoint rows per block ----
    int4 z; z.x = 0; z.y = 0; z.z = 0; z.w = 0;
    int4* prow = (int4*)(xq + ((long)b * HP + h + 1) * WP * CIN);
    if (tid < 8) prow[tid] = z;                       // col 0 of padded row h+1
    else if (tid < 16) prow[456 + tid - 8] = z;       // col 57 (57*8=456)
    if (h == 0) {
        int4* r0 = (int4*)(xq + (long)b * HP * WP * CIN);
        for (int i = tid; i < 464; i += 256) r0[i] = z;       // padded row 0
    } else if (h == H_ - 1) {
        int4* rt = (int4*)(xq + ((long)b * HP + 57) * WP * CIN);
        for (int i = tid; i < 464; i += 256) rt[i] = z;       // padded row 57
    }

    const int w = tid & 63;
    const int chi = tid >> 6;   // 0..3
    if (w < W_) {
        const float* xb = x + (long)b * CIN * HWP + h * W_ + w;
#pragma unroll
        for (int it = 0; it < 8; ++it) {
            const int c4 = it * 4 + chi;     // 0..31
            int pk = 0;
#pragma unroll
            for (int u = 0; u < 4; ++u) {
                float v = xb[(long)(c4 * 4 + u) * HWP];
                float q = fminf(127.f, fmaxf(-127.f, rintf(v * sx)));
                pk |= ((int)q & 0xff) << (u * 8);
            }
            ldsq[w * 33 + c4] = pk;
        }
    }
    __syncthreads();
    int4* dst = (int4*)(xq + (((long)b * HP + h + 1) * WP + 1) * CIN);
    for (int idx = tid; idx < W_ * 8; idx += 256) {
        const int ww = idx >> 3, c16 = idx & 7;
        int4 v;
        v.x = ldsq[ww * 33 + c16 * 4 + 0];
        v.y = ldsq[ww * 33 + c16 * 4 + 1];
        v.z = ldsq[ww * 33 + c16 * 4 + 2];
        v.w = ldsq[ww * 33 + c16 * 4 + 3];
        dst[ww * 8 + c16] = v;
    }
}

// ---------------- quantize w: OIHW f32 -> packed [chunk][cohalf][g][co128][16] int8 ----------------
__global__ __launch_bounds__(256) void quant_w_kernel(const float* __restrict__ wt,
        const unsigned* __restrict__ scales, signed char* __restrict__ wq) {
    const int id = blockIdx.x * 256 + threadIdx.x;   // 73728 total
    if (id >= COUT * 9 * 32) return;
    const float sw = 127.0f / __uint_as_float(scales[1]);
    const int co = id / 288;
    const int r  = id % 288;
    const int t  = r / 32;    // tap
    const int c4 = r % 32;    // ci/4
    int pk = 0;
#pragma unroll
    for (int u = 0; u < 4; ++u) {
        float v = wt[(co * CIN + c4 * 4 + u) * 9 + t];
        float q = fminf(127.f, fmaxf(-127.f, rintf(v * sw)));
        pk |= ((int)q & 0xff) << (u * 8);
    }
    const int k = t * CIN + c4 * 4;
    const int chunk = k >> 6;
    const int o = k & 63;
    *(int*)(wq + (long)chunk * WCHUNK + (co >> 7) * 8192 +
            (o >> 4) * 2048 + (co & 127) * 16 + (o & 15)) = pk;
}

// ---------------- conv: A-in-LDS ring + B-direct-to-reg MFMA implicit GEMM ----------------
// 256 thr = 4 waves; tile 128 co x 128 px; wave tile 64x64 (2x2 waves).
// LDS: 3-buffer A ring, 8KB each = 24KB -> 3 blocks/CU (VGPR cap via launch_bounds(256,3)).
// Per chunk: {vmcnt(6); s_barrier} -> stage A(c+2) (2 gld_lds) -> [sched_barrier]
//            -> load B(c+1) to regs (4x dwordx4) -> ds_read 4 A-frags -> 16 MFMA.
// FIFO guard (issue-order pinned): at TOP(c) ops newer than A(c) = B(c-1)+A(c+1)+B(c) = 10
// >= 6, so vmcnt(6) proves A(c) landed while keeping A(c+1)+B(c) in flight.
// Tail TOP(17): only B(17)=4 newer -> vmcnt(4).
__global__ __launch_bounds__(256, 3) void conv_kernel(
        const signed char* __restrict__ xq, const signed char* __restrict__ wq,
        const float* __restrict__ bias, const unsigned* __restrict__ scales,
        float* __restrict__ out) {
    __shared__ signed char smem[24576];   // A ring 3 x 8KB; epilogue reuses as f32 scratch

    const int tid = threadIdx.x;
    const int lane = tid & 63;
    const int wv = tid >> 6;        // 0..3
    const int ln = lane & 15;
    const int g  = lane >> 4;

    const int wco2 = wv >> 1;       // co half within block-co-tile
    const int wpx2 = wv & 1;        // px half

    // XCD-aware swizzle: 1568 blocks = 8 XCDs * 196; consecutive wg share px tile
    const int bid = blockIdx.x;
    const int wg  = (bid & 7) * 196 + (bid >> 3);
    const int pxt = wg >> 1;
    const int cot = wg & 1;
    const int px_blk = pxt * 128;
    const int cotoff = cot * 8192;

    // A staging: 2 gld_lds/chunk; wave stages 2x1KB contiguous
    const int aoff0 = wv * 1024 + lane * 16;
    const int aoff1 = aoff0 + 4096;

    // B per-lane voffsets: frag j, lane (ln,g) -> xq[px(j,ln), k = g*16 ...]
    int voff[4];
#pragma unroll
    for (int j = 0; j < 4; ++j) {
        const int pxs = px_blk + wpx2 * 64 + j * 16 + ln;
        const int bS = pxs / HWP, hwS = pxs % HWP;
        const int hS = hwS / W_, wS = hwS % W_;
        voff[j] = ((bS * HP + hS) * WP + wS) * CIN + g * 16;
    }
    const int voff0 = voff[0], voff1 = voff[1], voff2 = voff[2], voff3 = voff[3];

#define STAGE_A(c) { const int bf_ = (c) % 3; \
    gld_lds16(wq + (c) * WCHUNK + cotoff + aoff0, &smem[bf_ * 8192 + aoff0]); \
    gld_lds16(wq + (c) * WCHUNK + cotoff + aoff1, &smem[bf_ * 8192 + aoff1]); }

#define LOADB(c, BN) { const int tap_ = (c) >> 1; \
    const signed char* p_ = xq + ((tap_ / 3) * WP + (tap_ % 3)) * CIN + ((c) & 1) * 64; \
    BN##0 = *(const int4v*)(p_ + voff0); BN##1 = *(const int4v*)(p_ + voff1); \
    BN##2 = *(const int4v*)(p_ + voff2); BN##3 = *(const int4v*)(p_ + voff3); }

#define LDA_(i) (*(const int4v*)&smem[buf * 8192 + g * 2048 + (wco2 * 64 + (i) * 16 + ln) * 16])
#define MM(i, j, A, Bv) acc[i][j] = __builtin_amdgcn_mfma_i32_16x16x64_i8(A, Bv, acc[i][j], 0, 0, 0)

#define CHUNK(c, VM, BC, BN) { \
    const int buf = (c) % 3; \
    asm volatile("s_waitcnt vmcnt(" #VM ")\n\ts_barrier" ::: "memory"); \
    if ((c) + 2 < NCHUNK) STAGE_A((c) + 2); \
    __builtin_amdgcn_sched_barrier(0);  /* pin: B loads may not hoist above A gld_lds */ \
    if ((c) + 1 < NCHUNK) LOADB((c) + 1, BN); \
    int4v Af0 = LDA_(0), Af1 = LDA_(1), Af2 = LDA_(2), Af3 = LDA_(3); \
    __builtin_amdgcn_s_setprio(1); \
    MM(0, 0, Af0, BC##0); MM(0, 1, Af0, BC##1); MM(0, 2, Af0, BC##2); MM(0, 3, Af0, BC##3); \
    MM(1, 0, Af1, BC##0); MM(1, 1, Af1, BC##1); MM(1, 2, Af1, BC##2); MM(1, 3, Af1, BC##3); \
    MM(2, 0, Af2, BC##0); MM(2, 1, Af2, BC##1); MM(2, 2, Af2, BC##2); MM(2, 3, Af2, BC##3); \
    MM(3, 0, Af3, BC##0); MM(3, 1, Af3, BC##1); MM(3, 2, Af3, BC##2); MM(3, 3, Af3, BC##3); \
    __builtin_amdgcn_s_setprio(0); }

    int4v acc[4][4] = {};
    int4v Ba0, Ba1, Ba2, Ba3, Bb0, Bb1, Bb2, Bb3;
    STAGE_A(0);
    __builtin_amdgcn_sched_barrier(0);   // pin prologue issue order for FIFO counting
    STAGE_A(1);
    __builtin_amdgcn_sched_barrier(0);
    LOADB(0, Ba);
    CHUNK(0,  6, Ba, Bb) CHUNK(1,  6, Bb, Ba) CHUNK(2,  6, Ba, Bb) CHUNK(3,  6, Bb, Ba)
    CHUNK(4,  6, Ba, Bb) CHUNK(5,  6, Bb, Ba) CHUNK(6,  6, Ba, Bb) CHUNK(7,  6, Bb, Ba)
    CHUNK(8,  6, Ba, Bb) CHUNK(9,  6, Bb, Ba) CHUNK(10, 6, Ba, Bb) CHUNK(11, 6, Bb, Ba)
    CHUNK(12, 6, Ba, Bb) CHUNK(13, 6, Bb, Ba) CHUNK(14, 6, Ba, Bb) CHUNK(15, 6, Bb, Ba)
    CHUNK(16, 6, Ba, Bb) CHUNK(17, 4, Bb, Ba)
#undef CHUNK
#undef MM
#undef LDA_
#undef LOADB
#undef STAGE_A

    const float ax = __uint_as_float(scales[0]);
    const float aw = __uint_as_float(scales[1]);
    const float inv = 1.0f / ((127.0f / ax) * (127.0f / aw));

    // -------- epilogue: LDS transpose in 32-co rounds -> float4 stores --------
    // acc (i,j,r): co = cot*128 + wco2*64 + i*16 + g*4 + r; px = px_blk + wpx2*64 + j*16 + ln
    __syncthreads();
    float* ldsT = (float*)smem;            // [32 rows][stride 130 f32] = 16640 B

    const int c4 = tid & 31;               // float4 px column
    const int rsel = tid >> 5;             // 0..7
    const int px4 = px_blk + c4 * 4;
    const int bb = px4 / HWP, hw = px4 - bb * HWP;
    float* outb = out + ((long)bb * COUT + cot * 128) * HWP + hw;

#pragma unroll
    for (int rnd = 0; rnd < 4; ++rnd) {
        if (wco2 == (rnd >> 1)) {          // the 2 waves holding this 32-co band stage it
#pragma unroll
            for (int ii = 0; ii < 2; ++ii) {
                const int i = (rnd & 1) * 2 + ii;
#pragma unroll
                for (int r = 0; r < 4; ++r) {
                    const int cl = ii * 16 + g * 4 + r;   // 0..31
#pragma unroll
                    for (int j = 0; j < 4; ++j)
                        ldsT[cl * 130 + wpx2 * 64 + j * 16 + ln] = (float)acc[i][j][r] * inv;
                }
            }
        }
        __syncthreads();
#pragma unroll
        for (int rr = 0; rr < 4; ++rr) {
            const int row = rr * 8 + rsel;             // 0..31
            const int co = rnd * 32 + row;             // block-local co
            float4 v = *(float4*)&ldsT[row * 130 + c4 * 4];
            const float bsv = bias[cot * 128 + co];
            v.x += bsv; v.y += bsv; v.z += bsv; v.w += bsv;
            *(float4*)&outb[(long)co * HWP] = v;
        }
        if (rnd < 3) __syncthreads();
    }
}

extern "C" void kernel_launch(void* const* d_in, const int* in_sizes, int n_in,
                              void* d_out, int out_size, void* d_ws, size_t ws_size,
                              hipStream_t stream) {
    const float* x  = (const float*)d_in[0];
    const float* wt = (const float*)d_in[1];
    const float* bs = (const float*)d_in[2];
    float* out = (float*)d_out;

    unsigned* scales = (unsigned*)d_ws;                  // [0]=amax_x, [1]=amax_w (bits)
    const size_t XQ_OFF   = 256;
    const size_t XQ_BYTES = (size_t)B_ * HP * WP * CIN;  // 13,778,944
    signed char* xq = (signed char*)d_ws + XQ_OFF;
    signed char* wq = xq + XQ_BYTES;

    hipMemsetAsync(d_ws, 0, 8, stream);                  // zero the two amax slots

    const long n4x = (long)B_ * CIN * H_ * W_ / 4;
    const long n4w = (long)COUT * CIN * 9 / 4;
    amax_kernel<<<2176, 256, 0, stream>>>((const float4*)x, n4x, (const float4*)wt, n4w, scales);

    quant_x_kernel<<<B_ * H_, 256, 0, stream>>>(x, scales, xq);
    quant_w_kernel<<<(COUT * 9 * 32 + 255) / 256, 256, 0, stream>>>(wt, scales, wq);

    conv_kernel<<<2 * NPIX / 128, 256, 0, stream>>>(xq, wq, bs, scales, out);
}

// Round 6
// 214.465 us; speedup vs baseline: 1.1217x; 1.1217x over previous
//
#include <hip/hip_runtime.h>

// int8 quantized conv2d 3x3 s1 p1. B=32 Cin=128 H=W=56 Cout=256.
// Implicit GEMM. A and B both via 3-deep LDS rings staged with global_load_lds
// 2 chunks ahead (counted vmcnt(4), 1 barrier/chunk). 256-thr blocks,
// 128co x 128px tile, 48KB LDS -> 3 blocks/CU. XCD-swizzled, cot-coupled grid.

#define B_    32
#define CIN   128
#define H_    56
#define W_    56
#define COUT  256
#define HP    58
#define WP    58
#define HWP   (H_*W_)        // 3136
#define NPIX  (B_*HWP)       // 100352
#define NCHUNK 18            // K=1152 / 64
#define WCHUNK 16384         // wq bytes per chunk = 256co * 64B

typedef int int4v __attribute__((ext_vector_type(4)));

__device__ __forceinline__ void gld_lds16(const void* g, void* l) {
    __builtin_amdgcn_global_load_lds(
        (const __attribute__((address_space(1))) unsigned int*)g,
        (__attribute__((address_space(3))) unsigned int*)l, 16, 0, 0);
}

// ---------------- fused amax over x and w ----------------
__global__ __launch_bounds__(256) void amax_kernel(const float4* __restrict__ x, long n4x,
                                                   const float4* __restrict__ wt, long n4w,
                                                   unsigned* __restrict__ scales) {
    const float4* p; long n4; unsigned* slot; long start, stride;
    if (blockIdx.x < 2048) {
        p = x; n4 = n4x; slot = scales;
        start = (long)blockIdx.x * 256 + threadIdx.x; stride = 2048L * 256;
    } else {
        p = wt; n4 = n4w; slot = scales + 1;
        start = (long)(blockIdx.x - 2048) * 256 + threadIdx.x; stride = 128L * 256;
    }
    float m = 0.f;
    for (long i = start; i < n4; i += stride) {
        float4 v = p[i];
        m = fmaxf(m, fmaxf(fmaxf(fabsf(v.x), fabsf(v.y)), fmaxf(fabsf(v.z), fabsf(v.w))));
    }
    __shared__ float red[256];
    red[threadIdx.x] = m; __syncthreads();
    for (int s = 128; s > 0; s >>= 1) {
        if (threadIdx.x < s) red[threadIdx.x] = fmaxf(red[threadIdx.x], red[threadIdx.x + s]);
        __syncthreads();
    }
    if (threadIdx.x == 0) atomicMax(slot, __float_as_uint(red[0]));  // all >=0
}

// ---------------- quantize x: NCHW f32 -> padded NHWC int8 (+ border zeroing) ----------------
__global__ __launch_bounds__(256) void quant_x_kernel(const float* __restrict__ x,
        const unsigned* __restrict__ scales, signed char* __restrict__ xq) {
    const int bh = blockIdx.x;
    const int b = bh / H_, h = bh % H_;
    const float sx = 127.0f / __uint_as_float(scales[0]);
    __shared__ int ldsq[W_ * 33];
    const int tid = threadIdx.x;

    // ---- border padding; disjoint rows per block ----
    int4 z; z.x = 0; z.y = 0; z.z = 0; z.w = 0;
    int4* prow = (int4*)(xq + ((long)b * HP + h + 1) * WP * CIN);
    if (tid < 8) prow[tid] = z;                       // col 0 of padded row h+1
    else if (tid < 16) prow[456 + tid - 8] = z;       // col 57 (57*8=456)
    if (h == 0) {
        int4* r0 = (int4*)(xq + (long)b * HP * WP * CIN);
        for (int i = tid; i < 464; i += 256) r0[i] = z;       // padded row 0
    } else if (h == H_ - 1) {
        int4* rt = (int4*)(xq + ((long)b * HP + 57) * WP * CIN);
        for (int i = tid; i < 464; i += 256) rt[i] = z;       // padded row 57
    }

    const int w = tid & 63;
    const int chi = tid >> 6;   // 0..3
    if (w < W_) {
        const float* xb = x + (long)b * CIN * HWP + h * W_ + w;
#pragma unroll
        for (int it = 0; it < 8; ++it) {
            const int c4 = it * 4 + chi;     // 0..31
            int pk = 0;
#pragma unroll
            for (int u = 0; u < 4; ++u) {
                float v = xb[(long)(c4 * 4 + u) * HWP];
                float q = fminf(127.f, fmaxf(-127.f, rintf(v * sx)));
                pk |= ((int)q & 0xff) << (u * 8);
            }
            ldsq[w * 33 + c4] = pk;
        }
    }
    __syncthreads();
    int4* dst = (int4*)(xq + (((long)b * HP + h + 1) * WP + 1) * CIN);
    for (int idx = tid; idx < W_ * 8; idx += 256) {
        const int ww = idx >> 3, c16 = idx & 7;
        int4 v;
        v.x = ldsq[ww * 33 + c16 * 4 + 0];
        v.y = ldsq[ww * 33 + c16 * 4 + 1];
        v.z = ldsq[ww * 33 + c16 * 4 + 2];
        v.w = ldsq[ww * 33 + c16 * 4 + 3];
        dst[ww * 8 + c16] = v;
    }
}

// ---------------- quantize w: OIHW f32 -> packed [chunk][cohalf][g][co128][16] int8 ----------------
__global__ __launch_bounds__(256) void quant_w_kernel(const float* __restrict__ wt,
        const unsigned* __restrict__ scales, signed char* __restrict__ wq) {
    const int id = blockIdx.x * 256 + threadIdx.x;   // 73728 total
    if (id >= COUT * 9 * 32) return;
    const float sw = 127.0f / __uint_as_float(scales[1]);
    const int co = id / 288;
    const int r  = id % 288;
    const int t  = r / 32;    // tap
    const int c4 = r % 32;    // ci/4
    int pk = 0;
#pragma unroll
    for (int u = 0; u < 4; ++u) {
        float v = wt[(co * CIN + c4 * 4 + u) * 9 + t];
        float q = fminf(127.f, fmaxf(-127.f, rintf(v * sw)));
        pk |= ((int)q & 0xff) << (u * 8);
    }
    const int k = t * CIN + c4 * 4;
    const int chunk = k >> 6;
    const int o = k & 63;
    *(int*)(wq + (long)chunk * WCHUNK + (co >> 7) * 8192 +
            (o >> 4) * 2048 + (co & 127) * 16 + (o & 15)) = pk;
}

// ---------------- conv: dual 3-deep LDS rings, counted-vmcnt MFMA implicit GEMM ----------------
// 256 thr = 4 waves; tile 128 co x 128 px; wave tile 64x64 (2x2 waves).
// LDS: A ring 3x8KB @ [0,24K), B ring 3x8KB @ [24K,48K) -> 48KB -> 3 blocks/CU.
// Per chunk: {vmcnt(4); s_barrier} -> STAGE(c+2) (4 gld_lds, 2-deep prefetch)
//            -> ds_read 8 frags -> 16 MFMA.
// FIFO guard: at TOP(c), ops newer than body(c)'s last = body(c+1)'s 4 -> vmcnt(4)
// retires all of A(c)+B(c) while keeping A(c+1)+B(c+1) in flight. Tail: vmcnt(0).
// Bodies are issue-contained between asm memory-clobber barriers -> no sched pins.
__global__ __launch_bounds__(256, 3) void conv_kernel(
        const signed char* __restrict__ xq, const signed char* __restrict__ wq,
        const float* __restrict__ bias, const unsigned* __restrict__ scales,
        float* __restrict__ out) {
    __shared__ signed char smem[49152];   // rings; epilogue reuses as f32 scratch

    const int tid = threadIdx.x;
    const int lane = tid & 63;
    const int wv = tid >> 6;        // 0..3
    const int ln = lane & 15;
    const int g  = lane >> 4;

    const int wco2 = wv >> 1;       // co half within block-co-tile
    const int wpx2 = wv & 1;        // px half

    // XCD-aware swizzle: 1568 blocks = 8 XCDs * 196; wg pairs share px tile (B L2 reuse)
    const int bid = blockIdx.x;
    const int wg  = (bid & 7) * 196 + (bid >> 3);
    const int pxt = wg >> 1;
    const int cot = wg & 1;
    const int px_blk = pxt * 128;
    const int cotoff = cot * 8192;

    // A staging: wave stages 2x1KB contiguous (wq slice layout == A-LDS layout)
    const int aoff0 = wv * 1024 + lane * 16;
    const int aoff1 = aoff0 + 4096;

    // B staging: wave supplies g=wv for both px halves; per-lane px row address
    const int px0 = px_blk + lane;
    const int b0 = px0 / HWP, hw0 = px0 % HWP;
    const int voffB0 = ((b0 * HP + hw0 / W_) * WP + hw0 % W_) * CIN + wv * 16;
    const int px1 = px_blk + 64 + lane;
    const int b1 = px1 / HWP, hw1 = px1 % HWP;
    const int voffB1 = ((b1 * HP + hw1 / W_) * WP + hw1 % W_) * CIN + wv * 16;
    const int ldsB0 = wv * 2048 + lane * 16;
    const int ldsB1 = ldsB0 + 1024;

#define STAGE(c) { const int bf_ = (c) % 3; \
    gld_lds16(wq + (c) * WCHUNK + cotoff + aoff0, &smem[bf_ * 8192 + aoff0]); \
    gld_lds16(wq + (c) * WCHUNK + cotoff + aoff1, &smem[bf_ * 8192 + aoff1]); \
    const int tap_ = (c) >> 1; \
    const int toff_ = ((tap_ / 3) * WP + (tap_ % 3)) * CIN + ((c) & 1) * 64; \
    gld_lds16(xq + toff_ + voffB0, &smem[24576 + bf_ * 8192 + ldsB0]); \
    gld_lds16(xq + toff_ + voffB1, &smem[24576 + bf_ * 8192 + ldsB1]); }

#define LDA_(i) (*(const int4v*)&smem[buf * 8192 + g * 2048 + (wco2 * 64 + (i) * 16 + ln) * 16])
#define LDB_(j) (*(const int4v*)&smem[24576 + buf * 8192 + g * 2048 + (wpx2 * 64 + (j) * 16 + ln) * 16])
#define MM(i, j, A, Bv) acc[i][j] = __builtin_amdgcn_mfma_i32_16x16x64_i8(A, Bv, acc[i][j], 0, 0, 0)

#define CHUNK(c, VM) { \
    const int buf = (c) % 3; \
    asm volatile("s_waitcnt vmcnt(" #VM ")\n\ts_barrier" ::: "memory"); \
    if ((c) + 2 < NCHUNK) STAGE((c) + 2); \
    int4v Bf0 = LDB_(0), Bf1 = LDB_(1), Bf2 = LDB_(2), Bf3 = LDB_(3); \
    int4v Af0 = LDA_(0), Af1 = LDA_(1), Af2 = LDA_(2), Af3 = LDA_(3); \
    __builtin_amdgcn_s_setprio(1); \
    MM(0, 0, Af0, Bf0); MM(0, 1, Af0, Bf1); MM(0, 2, Af0, Bf2); MM(0, 3, Af0, Bf3); \
    MM(1, 0, Af1, Bf0); MM(1, 1, Af1, Bf1); MM(1, 2, Af1, Bf2); MM(1, 3, Af1, Bf3); \
    MM(2, 0, Af2, Bf0); MM(2, 1, Af2, Bf1); MM(2, 2, Af2, Bf2); MM(2, 3, Af2, Bf3); \
    MM(3, 0, Af3, Bf0); MM(3, 1, Af3, Bf1); MM(3, 2, Af3, Bf2); MM(3, 3, Af3, Bf3); \
    __builtin_amdgcn_s_setprio(0); }

    int4v acc[4][4] = {};
    STAGE(0);
    __builtin_amdgcn_sched_barrier(0);   // pin prologue body order for FIFO counting
    STAGE(1);
    CHUNK(0,  4) CHUNK(1,  4) CHUNK(2,  4) CHUNK(3,  4) CHUNK(4,  4) CHUNK(5,  4)
    CHUNK(6,  4) CHUNK(7,  4) CHUNK(8,  4) CHUNK(9,  4) CHUNK(10, 4) CHUNK(11, 4)
    CHUNK(12, 4) CHUNK(13, 4) CHUNK(14, 4) CHUNK(15, 4) CHUNK(16, 4) CHUNK(17, 0)
#undef CHUNK
#undef MM
#undef LDA_
#undef LDB_
#undef STAGE

    const float ax = __uint_as_float(scales[0]);
    const float aw = __uint_as_float(scales[1]);
    const float inv = 1.0f / ((127.0f / ax) * (127.0f / aw));

    // -------- epilogue: LDS transpose in 32-co rounds -> float4 stores --------
    // acc (i,j,r): co = cot*128 + wco2*64 + i*16 + g*4 + r; px = px_blk + wpx2*64 + j*16 + ln
    __syncthreads();
    float* ldsT = (float*)smem;            // [32 rows][stride 130 f32] = 16640 B

    const int c4 = tid & 31;               // float4 px column
    const int rsel = tid >> 5;             // 0..7
    const int px4 = px_blk + c4 * 4;
    const int bb = px4 / HWP, hw = px4 - bb * HWP;
    float* outb = out + ((long)bb * COUT + cot * 128) * HWP + hw;

#pragma unroll
    for (int rnd = 0; rnd < 4; ++rnd) {
        if (wco2 == (rnd >> 1)) {          // the 2 waves holding this 32-co band stage it
#pragma unroll
            for (int ii = 0; ii < 2; ++ii) {
                const int i = (rnd & 1) * 2 + ii;
#pragma unroll
                for (int r = 0; r < 4; ++r) {
                    const int cl = ii * 16 + g * 4 + r;   // 0..31
#pragma unroll
                    for (int j = 0; j < 4; ++j)
                        ldsT[cl * 130 + wpx2 * 64 + j * 16 + ln] = (float)acc[i][j][r] * inv;
                }
            }
        }
        __syncthreads();
#pragma unroll
        for (int rr = 0; rr < 4; ++rr) {
            const int row = rr * 8 + rsel;             // 0..31
            const int co = rnd * 32 + row;             // block-local co
            float4 v = *(float4*)&ldsT[row * 130 + c4 * 4];
            const float bsv = bias[cot * 128 + co];
            v.x += bsv; v.y += bsv; v.z += bsv; v.w += bsv;
            *(float4*)&outb[(long)co * HWP] = v;
        }
        if (rnd < 3) __syncthreads();
    }
}

extern "C" void kernel_launch(void* const* d_in, const int* in_sizes, int n_in,
                              void* d_out, int out_size, void* d_ws, size_t ws_size,
                              hipStream_t stream) {
    const float* x  = (const float*)d_in[0];
    const float* wt = (const float*)d_in[1];
    const float* bs = (const float*)d_in[2];
    float* out = (float*)d_out;

    unsigned* scales = (unsigned*)d_ws;                  // [0]=amax_x, [1]=amax_w (bits)
    const size_t XQ_OFF   = 256;
    const size_t XQ_BYTES = (size_t)B_ * HP * WP * CIN;  // 13,778,944
    signed char* xq = (signed char*)d_ws + XQ_OFF;
    signed char* wq = xq + XQ_BYTES;

    hipMemsetAsync(d_ws, 0, 8, stream);                  // zero the two amax slots

    const long n4x = (long)B_ * CIN * H_ * W_ / 4;
    const long n4w = (long)COUT * CIN * 9 / 4;
    amax_kernel<<<2176, 256, 0, stream>>>((const float4*)x, n4x, (const float4*)wt, n4w, scales);

    quant_x_kernel<<<B_ * H_, 256, 0, stream>>>(x, scales, xq);
    quant_w_kernel<<<(COUT * 9 * 32 + 255) / 256, 256, 0, stream>>>(wt, scales, wq);

    conv_kernel<<<2 * NPIX / 128, 256, 0, stream>>>(xq, wq, bs, scales, out);
}